// Round 10
// baseline (144.452 us; speedup 1.0000x reference)
//
#include <hip/hip_runtime.h>
#include <stdint.h>

#define N_NODES 100000
#define N_EDGES 1600000
#define HIDDEN  64
#define SLOPE   0.01f
#define NBUCK   782      // ceil(N_NODES/128): coarse buckets of 128 dst nodes
#define CAPB    2816     // fixed slots per bucket (mean 2048, sd 45 -> 17 sigma)
#define PCHUNK  6250     // edges per partition block; 256 * 6250 = 1.6M exactly
#define NPART   256      // 2.6x partition-CU coverage vs R8's 98
#define NSB     196      // scores blocks, 512 nodes each (196*512 = 100352)
                         // TOTAL GRID 256+196 = 452 <= 512 slots: ONE generation
                         // (R9's 641-block grid spilled 129 scores blocks into a
                         // 2nd generation -> serial tail masked the parallelism win)
#define NCAP    48       // per-node slot capacity (deg ~ Poisson(16); P(>48) ~ 3e-10)
#define NSTRIDE 50       // LDS record stride per node: 400 B de-banks the 4 quarters
#define EPT     7        // edges per thread (ceil(6250/1024)); tail-guarded

// ctrl layout: [0..NBUCK) bucket cursors (zeroed by hipMemsetAsync pre-launch)

// round-to-nearest-even fp32 -> bf16 (as ushort)
__device__ __forceinline__ unsigned short f2bf(float f) {
    uint32_t u = __float_as_uint(f);
    uint32_t r = u + 0x7FFFu + ((u >> 16) & 1u);
    return (unsigned short)(r >> 16);
}

// bf16-pair unpack helpers
__device__ __forceinline__ float bflo(uint32_t d) { return __uint_as_float(d << 16); }
__device__ __forceinline__ float bfhi(uint32_t d) { return __uint_as_float(d & 0xFFFF0000u); }

// K1: fused build. Blocks [0, NPART): LDS-sort one 6250-edge chunk by dst
//     bucket (edges register-cached, single global read), reserve once per
//     (block,bucket), copy out contiguous runs one bucket per 16-lane quarter.
//     Blocks [NPART, NPART+NSB): per-node scores + bf16 x copy, 512 nodes/block.
__global__ void __launch_bounds__(1024) k_build(const float* __restrict__ x,
                                                const float* __restrict__ w_i,
                                                const float* __restrict__ w_j,
                                                const int* __restrict__ srcs,
                                                const int* __restrict__ dsts,
                                                float* __restrict__ s_i,
                                                float* __restrict__ s_j,
                                                unsigned short* __restrict__ xb,
                                                int* __restrict__ ctrl,
                                                uint32_t* __restrict__ pairs) {
    __shared__ int lcnt[NBUCK], lloc[NBUCK], lbase[NBUCK];
    __shared__ int wsum[16];
    __shared__ uint32_t srec[PCHUNK];     // 25 KB
    int tid = threadIdx.x;
    if (blockIdx.x < NPART) {
        if (tid < NBUCK) lcnt[tid] = 0;
        __syncthreads();
        int e0 = blockIdx.x * PCHUNK;
        int e1 = min(e0 + PCHUNK, N_EDGES);
        // pass 1: load edges into registers (coalesced), count buckets
        int sr[EPT], dv[EPT];
#pragma unroll
        for (int k = 0; k < EPT; ++k) {
            int e = e0 + tid + k * 1024;
            bool val = e < e1;
            sr[k] = val ? srcs[e] : 0;
            dv[k] = val ? dsts[e] : -1;     // sentinel
        }
#pragma unroll
        for (int k = 0; k < EPT; ++k)
            if (dv[k] >= 0) atomicAdd(&lcnt[dv[k] >> 7], 1);
        __syncthreads();
        // wave-hierarchical exclusive scan of 782 counts (3 barriers)
        int v = (tid < NBUCK) ? lcnt[tid] : 0;
        int pre = v;
#pragma unroll
        for (int off = 1; off < 64; off <<= 1) {
            int t = __shfl_up(pre, off, 64);
            if ((tid & 63) >= off) pre += t;
        }
        if ((tid & 63) == 63) wsum[tid >> 6] = pre;
        __syncthreads();
        if (tid < 16) {
            int s = wsum[tid];
#pragma unroll
            for (int off = 1; off < 16; off <<= 1) {
                int t = __shfl_up(s, off, 64);
                if (tid >= off) s += t;
            }
            wsum[tid] = s;                    // inclusive
        }
        __syncthreads();
        int wavebase = (tid >> 6) ? wsum[(tid >> 6) - 1] : 0;
        // exclusive prefix; reserve global space; reset rank counter
        if (tid < NBUCK) {
            lloc[tid] = wavebase + pre - v;
            lbase[tid] = v ? atomicAdd(&ctrl[tid], v) : 0;
            lcnt[tid] = 0;                    // reuse as rank counter
        }
        __syncthreads();
        // pass 2: sort records into LDS by bucket (from registers)
#pragma unroll
        for (int k = 0; k < EPT; ++k) {
            if (dv[k] >= 0) {
                int b = dv[k] >> 7;
                int r = atomicAdd(&lcnt[b], 1);
                srec[lloc[b] + r] =
                    ((uint32_t)(dv[k] & 127) << 24) | (uint32_t)sr[k];
            }
        }
        __syncthreads();
        // copy-out: one bucket per 16-lane quarter (4 buckets per wave-iter)
        int wv = tid >> 6, ln = tid & 63;
        int q = ln >> 4, ql = ln & 15;
        for (int b = wv * 4 + q; b < NBUCK; b += 64) {
            int c = lcnt[b];
            int lo = lloc[b], go = lbase[b];
            for (int j = ql; j < c; j += 16) {
                int pos = go + j;
                if (pos < CAPB)           // 17-sigma guard, never taken
                    pairs[(size_t)b * CAPB + pos] = srec[lo + j];
            }
        }
        return;
    }
    // ---- scores: 16 lanes per node, float4 per lane, 512 nodes per block ----
    int u0 = blockIdx.x - NPART;
    int g16 = tid >> 4;
    int ql = tid & 15;
    float4 wi4 = ((const float4*)w_i)[ql];
    float4 wj4 = ((const float4*)w_j)[ql];
#pragma unroll
    for (int i = 0; i < 8; ++i) {
        int node = u0 * 512 + i * 64 + g16;
        if (node >= N_NODES) break;
        float4 v = ((const float4*)x)[node * 16 + ql];
        float a = v.x * wi4.x + v.y * wi4.y + v.z * wi4.z + v.w * wi4.w;
        float b = v.x * wj4.x + v.y * wj4.y + v.z * wj4.z + v.w * wj4.w;
#pragma unroll
        for (int off = 1; off < 16; off <<= 1) {
            a += __shfl_xor(a, off, 64);
            b += __shfl_xor(b, off, 64);
        }
        if (ql == 0) { s_i[node] = a; s_j[node] = b; }
        ushort4 o;
        o.x = f2bf(v.x); o.y = f2bf(v.y); o.z = f2bf(v.z); o.w = f2bf(v.w);
        ((ushort4*)xb)[node * 16 + ql] = o;
    }
}

// K2: one block per 128-node bucket, 1024 threads, 2 blocks/CU. UNCHANGED
//     (control, stable at 44.2-45.4 us across R5-R9): 16 lanes per node-row
//     (uint2), wave owns 8 nodes, 8 independent gathers in flight,
//     sched_barrier-pinned, no cross-lane reduce, coalesced stores.
__global__ void __launch_bounds__(1024, 8) k_bucket_agg(const uint2* __restrict__ xw2,
                                                        const uint32_t* __restrict__ pairs,
                                                        const int* __restrict__ ctrl,
                                                        const float* __restrict__ s_i,
                                                        const float* __restrict__ s_j,
                                                        float* __restrict__ out) {
    __shared__ uint64_t spairs[128 * NSTRIDE];   // 51.2 KB
    __shared__ int lcur[128];
    __shared__ float s_si[128];
    int tid = threadIdx.x;
    int cb = blockIdx.x;                  // one 128-node bucket per block
    int node0 = cb * 128;
    const uint32_t* reg = pairs + (size_t)cb * CAPB;
    int rcnt = min(ctrl[cb], CAPB);
    // zero-fill record slots: padded reads contribute w=0 with src=0 (row 0 hot)
    for (int i = tid; i < 128 * NSTRIDE; i += 1024) spairs[i] = 0ull;
    if (tid < 128) {
        lcur[tid] = 0;
        int node = node0 + tid;
        s_si[tid] = (node < N_NODES) ? s_i[node] : 0.f;
    }
    __syncthreads();
    // staging: 2-deep batched (rcnt mean 2048, sd 45); residual loop rare
    {
        int e0 = tid, e1 = tid + 1024;
        bool a0 = e0 < rcnt, a1 = e1 < rcnt;
        uint32_t p0 = a0 ? reg[e0] : 0u;
        uint32_t p1 = a1 ? reg[e1] : 0u;
        float sj0 = a0 ? s_j[p0 & 0xFFFFFFu] : 0.f;
        float sj1 = a1 ? s_j[p1 & 0xFFFFFFu] : 0.f;
        if (a0) {
            int n = (int)(p0 >> 24);
            float sc = s_si[n] + sj0;
            sc = (sc > 0.f) ? sc : SLOPE * sc;
            float w = __expf(sc);
            int slot = atomicAdd(&lcur[n], 1);
            if (slot < NCAP)
                spairs[n * NSTRIDE + slot] =
                    ((uint64_t)__float_as_uint(w) << 32) | (p0 & 0xFFFFFFu);
        }
        if (a1) {
            int n = (int)(p1 >> 24);
            float sc = s_si[n] + sj1;
            sc = (sc > 0.f) ? sc : SLOPE * sc;
            float w = __expf(sc);
            int slot = atomicAdd(&lcur[n], 1);
            if (slot < NCAP)
                spairs[n * NSTRIDE + slot] =
                    ((uint64_t)__float_as_uint(w) << 32) | (p1 & 0xFFFFFFu);
        }
        for (int e = tid + 2048; e < rcnt; e += 1024) {
            uint32_t p = reg[e];
            int n = (int)(p >> 24);
            float sc = s_si[n] + s_j[p & 0xFFFFFFu];
            sc = (sc > 0.f) ? sc : SLOPE * sc;
            float w = __expf(sc);
            int slot = atomicAdd(&lcur[n], 1);
            if (slot < NCAP)
                spairs[n * NSTRIDE + slot] =
                    ((uint64_t)__float_as_uint(w) << 32) | (p & 0xFFFFFFu);
        }
    }
    __syncthreads();
    int wave = tid >> 6, lane = tid & 63;
    int quarter = (lane >> 4) & 3;        // node selector within half
    int l16 = lane & 15;                  // 8 B chunk (4 dims) within row
    int kA = wave * 8 + quarter;          // half A node (0..127)
    int kB = kA + 4;                      // half B node
    int nodeA = node0 + kA, nodeB = node0 + kB;
    int cA = lcur[kA], cB = lcur[kB];
    int cqA = min(cA, NCAP), cqB = min(cB, NCAP);
    int mx = max(cqA, cqB);
    mx = max(mx, __shfl_xor(mx, 16, 64));
    mx = max(mx, __shfl_xor(mx, 32, 64));
    const uint64_t* ppA = spairs + kA * NSTRIDE;
    const uint64_t* ppB = spairs + kB * NSTRIDE;
    float accA[4] = {0.f, 0.f, 0.f, 0.f};
    float accB[4] = {0.f, 0.f, 0.f, 0.f};
    float denA = 0.f, denB = 0.f;
    for (int j = 0; j < mx; j += 4) {
        uint64_t rA[4], rB[4];
#pragma unroll
        for (int t = 0; t < 4; ++t) { rA[t] = ppA[j + t]; rB[t] = ppB[j + t]; }
        uint2 dA[4], dB[4];
#pragma unroll
        for (int t = 0; t < 4; ++t)
            dA[t] = xw2[((uint32_t)rA[t] & 0xFFFFFFu) * 16 + l16];
#pragma unroll
        for (int t = 0; t < 4; ++t)
            dB[t] = xw2[((uint32_t)rB[t] & 0xFFFFFFu) * 16 + l16];
        __builtin_amdgcn_sched_barrier(0);   // all 8 gathers issued before FMAs
#pragma unroll
        for (int t = 0; t < 4; ++t) {
            float w = __uint_as_float((uint32_t)(rA[t] >> 32));
            denA += w;
            accA[0] = fmaf(w, bflo(dA[t].x), accA[0]);
            accA[1] = fmaf(w, bfhi(dA[t].x), accA[1]);
            accA[2] = fmaf(w, bflo(dA[t].y), accA[2]);
            accA[3] = fmaf(w, bfhi(dA[t].y), accA[3]);
        }
#pragma unroll
        for (int t = 0; t < 4; ++t) {
            float w = __uint_as_float((uint32_t)(rB[t] >> 32));
            denB += w;
            accB[0] = fmaf(w, bflo(dB[t].x), accB[0]);
            accB[1] = fmaf(w, bfhi(dB[t].x), accB[1]);
            accB[2] = fmaf(w, bflo(dB[t].y), accB[2]);
            accB[3] = fmaf(w, bfhi(dB[t].y), accB[3]);
        }
    }
    // per-node overflow fallback (statistically unreachable)
    if (cA > NCAP) {
        denA = 0.f;
#pragma unroll
        for (int i = 0; i < 4; ++i) accA[i] = 0.f;
        for (int e = 0; e < rcnt; ++e) {
            uint32_t p = reg[e];
            if ((int)(p >> 24) == kA) {
                uint32_t src = p & 0xFFFFFFu;
                float sc = s_si[kA] + s_j[src];
                sc = (sc > 0.f) ? sc : SLOPE * sc;
                float w = __expf(sc);
                uint2 d = xw2[src * 16 + l16];
                denA += w;
                accA[0] = fmaf(w, bflo(d.x), accA[0]);
                accA[1] = fmaf(w, bfhi(d.x), accA[1]);
                accA[2] = fmaf(w, bflo(d.y), accA[2]);
                accA[3] = fmaf(w, bfhi(d.y), accA[3]);
            }
        }
    }
    if (cB > NCAP) {
        denB = 0.f;
#pragma unroll
        for (int i = 0; i < 4; ++i) accB[i] = 0.f;
        for (int e = 0; e < rcnt; ++e) {
            uint32_t p = reg[e];
            if ((int)(p >> 24) == kB) {
                uint32_t src = p & 0xFFFFFFu;
                float sc = s_si[kB] + s_j[src];
                sc = (sc > 0.f) ? sc : SLOPE * sc;
                float w = __expf(sc);
                uint2 d = xw2[src * 16 + l16];
                denB += w;
                accB[0] = fmaf(w, bflo(d.x), accB[0]);
                accB[1] = fmaf(w, bfhi(d.x), accB[1]);
                accB[2] = fmaf(w, bflo(d.y), accB[2]);
                accB[3] = fmaf(w, bfhi(d.y), accB[3]);
            }
        }
    }
    // epilogue: no cross-lane reduce — lane's acc[4] IS dims 4*l16..4*l16+3
    if (nodeA < N_NODES) {
        float4 r = make_float4(0.f, 0.f, 0.f, 0.f);
        if (cA > 0) {
            float inv = 1.f / denA;
            r.x = fmaxf(accA[0] * inv, 0.f);
            r.y = fmaxf(accA[1] * inv, 0.f);
            r.z = fmaxf(accA[2] * inv, 0.f);
            r.w = fmaxf(accA[3] * inv, 0.f);
        }
        ((float4*)(out + (size_t)nodeA * HIDDEN))[l16] = r;
    }
    if (nodeB < N_NODES) {
        float4 r = make_float4(0.f, 0.f, 0.f, 0.f);
        if (cB > 0) {
            float inv = 1.f / denB;
            r.x = fmaxf(accB[0] * inv, 0.f);
            r.y = fmaxf(accB[1] * inv, 0.f);
            r.z = fmaxf(accB[2] * inv, 0.f);
            r.w = fmaxf(accB[3] * inv, 0.f);
        }
        ((float4*)(out + (size_t)nodeB * HIDDEN))[l16] = r;
    }
}

extern "C" void kernel_launch(void* const* d_in, const int* in_sizes, int n_in,
                              void* d_out, int out_size, void* d_ws, size_t ws_size,
                              hipStream_t stream) {
    const float* x   = (const float*)d_in[0];
    const int*   ei  = (const int*)d_in[1];   // [2, E]: row0 = src (ej), row1 = dst (ei)
    const float* w_i = (const float*)d_in[2];
    const float* w_j = (const float*)d_in[3];
    float* out = (float*)d_out;

    char* p = (char*)d_ws;
    float*          s_i   = (float*)p;          p += (size_t)N_NODES * 4;
    float*          s_j   = (float*)p;          p += (size_t)N_NODES * 4;
    unsigned short* xb    = (unsigned short*)p; p += (size_t)N_NODES * HIDDEN * 2;
    int*            ctrl  = (int*)p;            p += 4096;
    uint32_t*       pairs = (uint32_t*)p;       // NBUCK * CAPB * 4 B = 8.8 MB

    const int* srcs = ei;             // edge_index[0]
    const int* dsts = ei + N_EDGES;   // edge_index[1]

    hipMemsetAsync(ctrl, 0, NBUCK * sizeof(int), stream);
    k_build     <<<NPART + NSB, 1024, 0, stream>>>(x, w_i, w_j, srcs, dsts,
                                                   s_i, s_j, xb, ctrl, pairs);
    k_bucket_agg<<<NBUCK, 1024, 0, stream>>>((const uint2*)xb, pairs, ctrl,
                                             s_i, s_j, out);
}

// Round 11
// 140.154 us; speedup vs baseline: 1.0307x; 1.0307x over previous
//
#include <hip/hip_runtime.h>
#include <stdint.h>

#define N_NODES 100000
#define N_EDGES 1600000
#define HIDDEN  64
#define SLOPE   0.01f
#define NBUCK   782      // ceil(N_NODES/128): coarse buckets of 128 dst nodes
#define CAPB    2816     // fixed slots per bucket (mean 2048, sd 45 -> 17 sigma)
#define PCHUNK  16384    // edges per partition block (98 blocks; 489 total = ONE generation)
#define NPART   98       // ceil(N_EDGES/PCHUNK)
#define NSB     391      // scores blocks, 256 nodes each (391*256 = 100096)
#define NCAP    48       // per-node slot capacity (deg ~ Poisson(16); P(>48) ~ 3e-10)
#define NSTRIDE 50       // LDS record stride per node: 400 B de-banks the 4 quarters
#define EPT     16       // edges per thread in a partition block (PCHUNK/1024)

// ctrl layout: [0..NBUCK) bucket cursors (zeroed by hipMemsetAsync pre-launch)
// R11 = exact revert to R8 (best measured, 140.5 us). R9/R10 proved partition
// parallelism regresses (cursor-atomic contention + per-block fixed overhead
// scale with NPART); R5-R7 proved agg is pinned at ~44 us by random-line
// service regardless of schedule or access order.

// round-to-nearest-even fp32 -> bf16 (as ushort)
__device__ __forceinline__ unsigned short f2bf(float f) {
    uint32_t u = __float_as_uint(f);
    uint32_t r = u + 0x7FFFu + ((u >> 16) & 1u);
    return (unsigned short)(r >> 16);
}

// bf16-pair unpack helpers
__device__ __forceinline__ float bflo(uint32_t d) { return __uint_as_float(d << 16); }
__device__ __forceinline__ float bfhi(uint32_t d) { return __uint_as_float(d & 0xFFFF0000u); }

// K1: fused build. Blocks [0, NPART): LDS-sort one 16384-edge chunk by dst
//     bucket (edges register-cached in pass 1 -> single global read), reserve
//     once per (block,bucket), copy out contiguous runs one bucket per
//     16-lane quarter. Blocks [NPART, NPART+NSB): per-node scores + bf16 x.
__global__ void __launch_bounds__(1024) k_build(const float* __restrict__ x,
                                                const float* __restrict__ w_i,
                                                const float* __restrict__ w_j,
                                                const int* __restrict__ srcs,
                                                const int* __restrict__ dsts,
                                                float* __restrict__ s_i,
                                                float* __restrict__ s_j,
                                                unsigned short* __restrict__ xb,
                                                int* __restrict__ ctrl,
                                                uint32_t* __restrict__ pairs) {
    __shared__ int lcnt[NBUCK], lloc[NBUCK], lbase[NBUCK];
    __shared__ int wsum[16];
    __shared__ uint32_t srec[PCHUNK];     // 64 KB
    int tid = threadIdx.x;
    if (blockIdx.x < NPART) {
        if (tid < NBUCK) lcnt[tid] = 0;
        __syncthreads();
        int e0 = blockIdx.x * PCHUNK;
        int e1 = min(e0 + PCHUNK, N_EDGES);
        // pass 1: load 16 edges into registers (coalesced), count buckets
        int sr[EPT], dv[EPT];
#pragma unroll
        for (int k = 0; k < EPT; ++k) {
            int e = e0 + tid + k * 1024;
            bool val = e < e1;
            sr[k] = val ? srcs[e] : 0;
            dv[k] = val ? dsts[e] : -1;     // sentinel for tail chunk
        }
#pragma unroll
        for (int k = 0; k < EPT; ++k)
            if (dv[k] >= 0) atomicAdd(&lcnt[dv[k] >> 7], 1);
        __syncthreads();
        // wave-hierarchical exclusive scan of 782 counts (3 barriers)
        int v = (tid < NBUCK) ? lcnt[tid] : 0;
        int pre = v;
#pragma unroll
        for (int off = 1; off < 64; off <<= 1) {
            int t = __shfl_up(pre, off, 64);
            if ((tid & 63) >= off) pre += t;
        }
        if ((tid & 63) == 63) wsum[tid >> 6] = pre;
        __syncthreads();
        if (tid < 16) {
            int s = wsum[tid];
#pragma unroll
            for (int off = 1; off < 16; off <<= 1) {
                int t = __shfl_up(s, off, 64);
                if (tid >= off) s += t;
            }
            wsum[tid] = s;                    // inclusive
        }
        __syncthreads();
        int wavebase = (tid >> 6) ? wsum[(tid >> 6) - 1] : 0;
        // exclusive prefix; reserve global space; reset rank counter
        if (tid < NBUCK) {
            lloc[tid] = wavebase + pre - v;
            lbase[tid] = v ? atomicAdd(&ctrl[tid], v) : 0;
            lcnt[tid] = 0;                    // reuse as rank counter
        }
        __syncthreads();
        // pass 2: sort records into LDS by bucket (from registers)
#pragma unroll
        for (int k = 0; k < EPT; ++k) {
            if (dv[k] >= 0) {
                int b = dv[k] >> 7;
                int r = atomicAdd(&lcnt[b], 1);
                srec[lloc[b] + r] =
                    ((uint32_t)(dv[k] & 127) << 24) | (uint32_t)sr[k];
            }
        }
        __syncthreads();
        // copy-out: one bucket per 16-lane quarter (4 buckets per wave-iter)
        int wv = tid >> 6, ln = tid & 63;
        int q = ln >> 4, ql = ln & 15;
        for (int b = wv * 4 + q; b < NBUCK; b += 64) {
            int c = lcnt[b];
            int lo = lloc[b], go = lbase[b];
            for (int j = ql; j < c; j += 16) {
                int pos = go + j;
                if (pos < CAPB)           // 17-sigma guard, never taken
                    pairs[(size_t)b * CAPB + pos] = srec[lo + j];
            }
        }
        return;
    }
    // ---- scores: 16 lanes per node, float4 per lane, 256 nodes per block ----
    int u0 = blockIdx.x - NPART;
    int g16 = tid >> 4;
    int ql = tid & 15;
    float4 wi4 = ((const float4*)w_i)[ql];
    float4 wj4 = ((const float4*)w_j)[ql];
#pragma unroll
    for (int i = 0; i < 4; ++i) {
        int node = u0 * 256 + i * 64 + g16;
        if (node >= N_NODES) break;
        float4 v = ((const float4*)x)[node * 16 + ql];
        float a = v.x * wi4.x + v.y * wi4.y + v.z * wi4.z + v.w * wi4.w;
        float b = v.x * wj4.x + v.y * wj4.y + v.z * wj4.z + v.w * wj4.w;
#pragma unroll
        for (int off = 1; off < 16; off <<= 1) {
            a += __shfl_xor(a, off, 64);
            b += __shfl_xor(b, off, 64);
        }
        if (ql == 0) { s_i[node] = a; s_j[node] = b; }
        ushort4 o;
        o.x = f2bf(v.x); o.y = f2bf(v.y); o.z = f2bf(v.z); o.w = f2bf(v.w);
        ((ushort4*)xb)[node * 16 + ql] = o;
    }
}

// K2: one block per 128-node bucket, 1024 threads, 2 blocks/CU. Stable at
//     44.2 +/- 0.6 us across R5-R10 (6 schedules): 16 lanes per node-row
//     (uint2), wave owns 8 nodes, 8 independent gathers in flight,
//     sched_barrier-pinned, no cross-lane reduce, coalesced stores.
__global__ void __launch_bounds__(1024, 8) k_bucket_agg(const uint2* __restrict__ xw2,
                                                        const uint32_t* __restrict__ pairs,
                                                        const int* __restrict__ ctrl,
                                                        const float* __restrict__ s_i,
                                                        const float* __restrict__ s_j,
                                                        float* __restrict__ out) {
    __shared__ uint64_t spairs[128 * NSTRIDE];   // 51.2 KB
    __shared__ int lcur[128];
    __shared__ float s_si[128];
    int tid = threadIdx.x;
    int cb = blockIdx.x;                  // one 128-node bucket per block
    int node0 = cb * 128;
    const uint32_t* reg = pairs + (size_t)cb * CAPB;
    int rcnt = min(ctrl[cb], CAPB);
    // zero-fill record slots: padded reads contribute w=0 with src=0 (row 0 hot)
    for (int i = tid; i < 128 * NSTRIDE; i += 1024) spairs[i] = 0ull;
    if (tid < 128) {
        lcur[tid] = 0;
        int node = node0 + tid;
        s_si[tid] = (node < N_NODES) ? s_i[node] : 0.f;
    }
    __syncthreads();
    // staging: 2-deep batched (rcnt mean 2048, sd 45); residual loop rare
    {
        int e0 = tid, e1 = tid + 1024;
        bool a0 = e0 < rcnt, a1 = e1 < rcnt;
        uint32_t p0 = a0 ? reg[e0] : 0u;
        uint32_t p1 = a1 ? reg[e1] : 0u;
        float sj0 = a0 ? s_j[p0 & 0xFFFFFFu] : 0.f;
        float sj1 = a1 ? s_j[p1 & 0xFFFFFFu] : 0.f;
        if (a0) {
            int n = (int)(p0 >> 24);
            float sc = s_si[n] + sj0;
            sc = (sc > 0.f) ? sc : SLOPE * sc;
            float w = __expf(sc);
            int slot = atomicAdd(&lcur[n], 1);
            if (slot < NCAP)
                spairs[n * NSTRIDE + slot] =
                    ((uint64_t)__float_as_uint(w) << 32) | (p0 & 0xFFFFFFu);
        }
        if (a1) {
            int n = (int)(p1 >> 24);
            float sc = s_si[n] + sj1;
            sc = (sc > 0.f) ? sc : SLOPE * sc;
            float w = __expf(sc);
            int slot = atomicAdd(&lcur[n], 1);
            if (slot < NCAP)
                spairs[n * NSTRIDE + slot] =
                    ((uint64_t)__float_as_uint(w) << 32) | (p1 & 0xFFFFFFu);
        }
        for (int e = tid + 2048; e < rcnt; e += 1024) {
            uint32_t p = reg[e];
            int n = (int)(p >> 24);
            float sc = s_si[n] + s_j[p & 0xFFFFFFu];
            sc = (sc > 0.f) ? sc : SLOPE * sc;
            float w = __expf(sc);
            int slot = atomicAdd(&lcur[n], 1);
            if (slot < NCAP)
                spairs[n * NSTRIDE + slot] =
                    ((uint64_t)__float_as_uint(w) << 32) | (p & 0xFFFFFFu);
        }
    }
    __syncthreads();
    int wave = tid >> 6, lane = tid & 63;
    int quarter = (lane >> 4) & 3;        // node selector within half
    int l16 = lane & 15;                  // 8 B chunk (4 dims) within row
    int kA = wave * 8 + quarter;          // half A node (0..127)
    int kB = kA + 4;                      // half B node
    int nodeA = node0 + kA, nodeB = node0 + kB;
    int cA = lcur[kA], cB = lcur[kB];
    int cqA = min(cA, NCAP), cqB = min(cB, NCAP);
    int mx = max(cqA, cqB);
    mx = max(mx, __shfl_xor(mx, 16, 64));
    mx = max(mx, __shfl_xor(mx, 32, 64));
    const uint64_t* ppA = spairs + kA * NSTRIDE;
    const uint64_t* ppB = spairs + kB * NSTRIDE;
    float accA[4] = {0.f, 0.f, 0.f, 0.f};
    float accB[4] = {0.f, 0.f, 0.f, 0.f};
    float denA = 0.f, denB = 0.f;
    for (int j = 0; j < mx; j += 4) {
        uint64_t rA[4], rB[4];
#pragma unroll
        for (int t = 0; t < 4; ++t) { rA[t] = ppA[j + t]; rB[t] = ppB[j + t]; }
        uint2 dA[4], dB[4];
#pragma unroll
        for (int t = 0; t < 4; ++t)
            dA[t] = xw2[((uint32_t)rA[t] & 0xFFFFFFu) * 16 + l16];
#pragma unroll
        for (int t = 0; t < 4; ++t)
            dB[t] = xw2[((uint32_t)rB[t] & 0xFFFFFFu) * 16 + l16];
        __builtin_amdgcn_sched_barrier(0);   // all 8 gathers issued before FMAs
#pragma unroll
        for (int t = 0; t < 4; ++t) {
            float w = __uint_as_float((uint32_t)(rA[t] >> 32));
            denA += w;
            accA[0] = fmaf(w, bflo(dA[t].x), accA[0]);
            accA[1] = fmaf(w, bfhi(dA[t].x), accA[1]);
            accA[2] = fmaf(w, bflo(dA[t].y), accA[2]);
            accA[3] = fmaf(w, bfhi(dA[t].y), accA[3]);
        }
#pragma unroll
        for (int t = 0; t < 4; ++t) {
            float w = __uint_as_float((uint32_t)(rB[t] >> 32));
            denB += w;
            accB[0] = fmaf(w, bflo(dB[t].x), accB[0]);
            accB[1] = fmaf(w, bfhi(dB[t].x), accB[1]);
            accB[2] = fmaf(w, bflo(dB[t].y), accB[2]);
            accB[3] = fmaf(w, bfhi(dB[t].y), accB[3]);
        }
    }
    // per-node overflow fallback (statistically unreachable)
    if (cA > NCAP) {
        denA = 0.f;
#pragma unroll
        for (int i = 0; i < 4; ++i) accA[i] = 0.f;
        for (int e = 0; e < rcnt; ++e) {
            uint32_t p = reg[e];
            if ((int)(p >> 24) == kA) {
                uint32_t src = p & 0xFFFFFFu;
                float sc = s_si[kA] + s_j[src];
                sc = (sc > 0.f) ? sc : SLOPE * sc;
                float w = __expf(sc);
                uint2 d = xw2[src * 16 + l16];
                denA += w;
                accA[0] = fmaf(w, bflo(d.x), accA[0]);
                accA[1] = fmaf(w, bfhi(d.x), accA[1]);
                accA[2] = fmaf(w, bflo(d.y), accA[2]);
                accA[3] = fmaf(w, bfhi(d.y), accA[3]);
            }
        }
    }
    if (cB > NCAP) {
        denB = 0.f;
#pragma unroll
        for (int i = 0; i < 4; ++i) accB[i] = 0.f;
        for (int e = 0; e < rcnt; ++e) {
            uint32_t p = reg[e];
            if ((int)(p >> 24) == kB) {
                uint32_t src = p & 0xFFFFFFu;
                float sc = s_si[kB] + s_j[src];
                sc = (sc > 0.f) ? sc : SLOPE * sc;
                float w = __expf(sc);
                uint2 d = xw2[src * 16 + l16];
                denB += w;
                accB[0] = fmaf(w, bflo(d.x), accB[0]);
                accB[1] = fmaf(w, bfhi(d.x), accB[1]);
                accB[2] = fmaf(w, bflo(d.y), accB[2]);
                accB[3] = fmaf(w, bfhi(d.y), accB[3]);
            }
        }
    }
    // epilogue: no cross-lane reduce — lane's acc[4] IS dims 4*l16..4*l16+3
    if (nodeA < N_NODES) {
        float4 r = make_float4(0.f, 0.f, 0.f, 0.f);
        if (cA > 0) {
            float inv = 1.f / denA;
            r.x = fmaxf(accA[0] * inv, 0.f);
            r.y = fmaxf(accA[1] * inv, 0.f);
            r.z = fmaxf(accA[2] * inv, 0.f);
            r.w = fmaxf(accA[3] * inv, 0.f);
        }
        ((float4*)(out + (size_t)nodeA * HIDDEN))[l16] = r;
    }
    if (nodeB < N_NODES) {
        float4 r = make_float4(0.f, 0.f, 0.f, 0.f);
        if (cB > 0) {
            float inv = 1.f / denB;
            r.x = fmaxf(accB[0] * inv, 0.f);
            r.y = fmaxf(accB[1] * inv, 0.f);
            r.z = fmaxf(accB[2] * inv, 0.f);
            r.w = fmaxf(accB[3] * inv, 0.f);
        }
        ((float4*)(out + (size_t)nodeB * HIDDEN))[l16] = r;
    }
}

extern "C" void kernel_launch(void* const* d_in, const int* in_sizes, int n_in,
                              void* d_out, int out_size, void* d_ws, size_t ws_size,
                              hipStream_t stream) {
    const float* x   = (const float*)d_in[0];
    const int*   ei  = (const int*)d_in[1];   // [2, E]: row0 = src (ej), row1 = dst (ei)
    const float* w_i = (const float*)d_in[2];
    const float* w_j = (const float*)d_in[3];
    float* out = (float*)d_out;

    char* p = (char*)d_ws;
    float*          s_i   = (float*)p;          p += (size_t)N_NODES * 4;
    float*          s_j   = (float*)p;          p += (size_t)N_NODES * 4;
    unsigned short* xb    = (unsigned short*)p; p += (size_t)N_NODES * HIDDEN * 2;
    int*            ctrl  = (int*)p;            p += 4096;
    uint32_t*       pairs = (uint32_t*)p;       // NBUCK * CAPB * 4 B = 8.8 MB

    const int* srcs = ei;             // edge_index[0]
    const int* dsts = ei + N_EDGES;   // edge_index[1]

    hipMemsetAsync(ctrl, 0, NBUCK * sizeof(int), stream);
    k_build     <<<NPART + NSB, 1024, 0, stream>>>(x, w_i, w_j, srcs, dsts,
                                                   s_i, s_j, xb, ctrl, pairs);
    k_bucket_agg<<<NBUCK, 1024, 0, stream>>>((const uint2*)xb, pairs, ctrl,
                                             s_i, s_j, out);
}